// Round 4
// baseline (126.723 us; speedup 1.0000x reference)
//
#include <hip/hip_runtime.h>

#define DM 2048
#define NG 64
#define EPSV 1e-8f
#define TAU 1e-3f

typedef __attribute__((ext_vector_type(4))) float f32x4;
typedef __attribute__((ext_vector_type(16))) float f32x16;
typedef __attribute__((ext_vector_type(4))) int i32x4;
typedef __attribute__((ext_vector_type(4))) unsigned int u32x4;
typedef __attribute__((ext_vector_type(8))) short bf16x8;

__device__ __forceinline__ void stage16(const float* gsrc, float* ldst) {
  __builtin_amdgcn_global_load_lds(
      (const __attribute__((address_space(1))) unsigned int*)gsrc,
      (__attribute__((address_space(3))) unsigned int*)ldst, 16, 0, 0);
}

// split 8 fp32 (two f32x4) into hi/lo bf16 fragments.
// hi = truncate-to-bf16 (exact residual), lo = rne(x - hi_f32).
__device__ __forceinline__ void split8(f32x4 x0, f32x4 x1, bf16x8& ah, bf16x8& al) {
  u32x4 u0 = __builtin_bit_cast(u32x4, x0);
  u32x4 u1 = __builtin_bit_cast(u32x4, x1);
  i32x4 hi;
  hi.x = (int)((u0.x >> 16) | (u0.y & 0xffff0000u));
  hi.y = (int)((u0.z >> 16) | (u0.w & 0xffff0000u));
  hi.z = (int)((u1.x >> 16) | (u1.y & 0xffff0000u));
  hi.w = (int)((u1.z >> 16) | (u1.w & 0xffff0000u));
  u32x4 m0 = u0 & 0xffff0000u;
  u32x4 m1 = u1 & 0xffff0000u;
  f32x4 r0 = x0 - __builtin_bit_cast(f32x4, m0);
  f32x4 r1 = x1 - __builtin_bit_cast(f32x4, m1);
  int lo0, lo1, lo2, lo3;
  asm("v_cvt_pk_bf16_f32 %0, %1, %2" : "=v"(lo0) : "v"(r0.x), "v"(r0.y));
  asm("v_cvt_pk_bf16_f32 %0, %1, %2" : "=v"(lo1) : "v"(r0.z), "v"(r0.w));
  asm("v_cvt_pk_bf16_f32 %0, %1, %2" : "=v"(lo2) : "v"(r1.x), "v"(r1.y));
  asm("v_cvt_pk_bf16_f32 %0, %1, %2" : "=v"(lo3) : "v"(r1.z), "v"(r1.w));
  i32x4 lo; lo.x = lo0; lo.y = lo1; lo.z = lo2; lo.w = lo3;
  ah = __builtin_bit_cast(bf16x8, hi);
  al = __builtin_bit_cast(bf16x8, lo);
}

// ---------------- Kernel 0: W split + counter reset ----------------
// Fragment-ordered layout: element (S,h,n,j) at ((S*2+h)*64+n)*8+j,
// S=kstep(0..127), h=lane-half, n=group, j=0..7 (k = S*16 + h*8 + j).
__global__ __launch_bounds__(256) void moe_prep(
    const float* __restrict__ W, unsigned short* __restrict__ whp,
    unsigned short* __restrict__ wlp, int* __restrict__ counter)
{
  int tg = blockIdx.x * 256 + threadIdx.x;   // 0..16383 = 128*2*64 fragments
  if (tg == 0) *counter = 0;
  int S = tg >> 7, h = (tg >> 6) & 1, n = tg & 63;
  const float* src = &W[(size_t)n * DM + S * 16 + h * 8];
  f32x4 w0 = *(const f32x4*)&src[0];
  f32x4 w1 = *(const f32x4*)&src[4];
  bf16x8 ah, al;
  split8(w0, w1, ah, al);
  *(bf16x8*)&whp[(size_t)tg * 8] = ah;
  *(bf16x8*)&wlp[(size_t)tg * 8] = al;
}

// ---------------- Kernel 1: split-bf16 MFMA GEMM + softmax/top-8 + flag ----------------
// Block = 64 tok x 64 grp, 4 waves (wave = 32x32 tile). K windows of 64,
// RING-5 LDS for x (fp32), counted vmcnt(16), raw s_barrier. B from global (L2).
__global__ __launch_bounds__(256, 1) void moe_mfma(
    const float* __restrict__ x, const unsigned short* __restrict__ whp,
    const unsigned short* __restrict__ wlp, float* __restrict__ out,
    int* __restrict__ counter, int* __restrict__ flaglist, int mtok)
{
  __shared__ float xsr[5][64 * 64];   // 80 KB
  __shared__ float lbuf[64][64];      // 16 KB

  const int tid = threadIdx.x;
  const int lane = tid & 63;
  const int wid = tid >> 6;
  const int tm0 = (wid & 1) * 32;
  const int gn0 = (wid >> 1) * 32;
  const int tok0 = blockIdx.x * 64;
  const int h = lane >> 5;
  const int ln = lane & 31;
  const int grp = gn0 + ln;

  // stage x window w (64 k) into ring slot; source pre-swizzled, LDS linear.
  auto stage_window = [&](int w, int slot) {
    const float* xb = x + (size_t)tok0 * DM + w * 64;
    float* ld = &xsr[slot][0];
#pragma unroll
    for (int i = 0; i < 4; ++i) {
      int idx = i * 256 + tid;
      int r = idx >> 4, q = idx & 15;
      int sq = q ^ (r & 15);
      stage16(xb + (size_t)r * DM + (sq << 2), ld + (idx << 2));
    }
  };

  bf16x8 Bh[2][4], Bl[2][4];
  f32x16 acc = {0.f,0.f,0.f,0.f,0.f,0.f,0.f,0.f,0.f,0.f,0.f,0.f,0.f,0.f,0.f,0.f};

#define LOADB(WW, SET) do {                                                  \
    int w_ = (WW) < 31 ? (WW) : 31;                                          \
    _Pragma("unroll")                                                        \
    for (int s = 0; s < 4; ++s) {                                            \
      size_t bidx = (((size_t)((w_ * 4 + s) * 2 + h) * 64) + grp) * 8;       \
      Bh[SET][s] = *(const bf16x8*)&whp[bidx];                               \
      Bl[SET][s] = *(const bf16x8*)&wlp[bidx];                               \
    }                                                                        \
  } while (0)

#define COMPUTE(WIN, SET) do {                                               \
    const float* xrow_ = &xsr[(WIN) % 5][(tm0 + ln) * 64];                   \
    const int rsw_ = ((tm0 + ln) & 15);                                      \
    _Pragma("unroll")                                                        \
    for (int s = 0; s < 4; ++s) {                                            \
      int qa = s * 4 + h * 2;                                                \
      f32x4 x0 = *(const f32x4*)&xrow_[((qa ^ rsw_) << 2)];                  \
      f32x4 x1 = *(const f32x4*)&xrow_[(((qa + 1) ^ rsw_) << 2)];            \
      bf16x8 ah, al;                                                         \
      split8(x0, x1, ah, al);                                                \
      acc = __builtin_amdgcn_mfma_f32_32x32x16_bf16(ah, Bh[SET][s], acc, 0, 0, 0); \
      acc = __builtin_amdgcn_mfma_f32_32x32x16_bf16(al, Bh[SET][s], acc, 0, 0, 0); \
      acc = __builtin_amdgcn_mfma_f32_32x32x16_bf16(ah, Bl[SET][s], acc, 0, 0, 0); \
    }                                                                        \
  } while (0)

  // prologue: B(0) then 3 staged windows (FIFO: B0,s0,s1,s2)
  LOADB(0, 0);
  stage_window(0, 0);
  stage_window(1, 1);
  stage_window(2, 2);

#pragma unroll 1
  for (int w2 = 0; w2 < 16; ++w2) {
    int win = w2 * 2;
    LOADB(win + 1, 1);
    stage_window((win + 3) < 31 ? (win + 3) : 31, (win + 3) % 5);
    asm volatile("s_waitcnt vmcnt(16)" ::: "memory");
    __builtin_amdgcn_s_barrier();
    COMPUTE(win, 0);

    LOADB(win + 2, 0);
    stage_window((win + 4) < 31 ? (win + 4) : 31, (win + 4) % 5);
    asm volatile("s_waitcnt vmcnt(16)" ::: "memory");
    __builtin_amdgcn_s_barrier();
    COMPUTE(win + 1, 1);
  }
#undef LOADB
#undef COMPUTE

  // ---- logits -> LDS (quad-rotate swizzled cols) ----
  // C/D map (guide-verified): n = gn0 + (lane&31); m = tm0 + (r&3)+8*(r>>2)+4*(lane>>5)
#pragma unroll
  for (int r = 0; r < 16; ++r) {
    int m = tm0 + (r & 3) + 8 * (r >> 2) + 4 * h;
    int colp = ((gn0 + ln) + 4 * (m & 15)) & 63;
    lbuf[m][colp] = acc[r];
  }
  __syncthreads();

  // ---- per-token epilogue: 4 lanes/token, 16 groups/lane ----
  const int t = tid >> 2;
  const int l4 = tid & 3;
  float l[16], e[16];
#pragma unroll
  for (int jj = 0; jj < 4; ++jj) {
    int gb = l4 * 16 + jj * 4;
    int cp = (gb + 4 * (t & 15)) & 63;
    f32x4 v = *(const f32x4*)&lbuf[t][cp];
    l[jj * 4 + 0] = v.x; l[jj * 4 + 1] = v.y;
    l[jj * 4 + 2] = v.z; l[jj * 4 + 3] = v.w;
  }
  float mx = l[0];
#pragma unroll
  for (int j = 1; j < 16; ++j) mx = fmaxf(mx, l[j]);
  mx = fmaxf(mx, __shfl_xor(mx, 1));
  mx = fmaxf(mx, __shfl_xor(mx, 2));
  float sum = 0.f;
#pragma unroll
  for (int j = 0; j < 16; ++j) { e[j] = __expf(l[j] - mx); sum += e[j]; }
  sum += __shfl_xor(sum, 1);
  sum += __shfl_xor(sum, 2);

  // top-8 by logit (monotone with score); 9th pass for the gap flag
  unsigned taken = 0;
  float l8 = 0.f, l9 = 0.f;
#pragma unroll 1
  for (int p = 0; p < 9; ++p) {
    float bv = -3.4e38f; int bi = 1000;
#pragma unroll
    for (int j = 0; j < 16; ++j) {
      bool avail = !((taken >> j) & 1u);
      bool better = avail && (l[j] > bv);
      bv = better ? l[j] : bv;
      bi = better ? (l4 * 16 + j) : bi;
    }
#pragma unroll
    for (int msk = 1; msk < 4; msk <<= 1) {
      float ov = __shfl_xor(bv, msk);
      int oi = __shfl_xor(bi, msk);
      bool better = (ov > bv) || (ov == bv && oi < bi);
      bv = better ? ov : bv;
      bi = better ? oi : bi;
    }
    if (p < 8) {
      if ((bi >> 4) == l4) taken |= 1u << (bi & 15);
      if (p == 7) l8 = bv;
    } else {
      l9 = bv;
    }
  }
  float esel = 0.f;
#pragma unroll
  for (int j = 0; j < 16; ++j) esel += ((taken >> j) & 1u) ? e[j] : 0.f;
  esel += __shfl_xor(esel, 1);
  esel += __shfl_xor(esel, 2);

  if ((l8 - l9) < TAU && l4 == 0) {
    int ix = atomicAdd(counter, 1);
    flaglist[ix] = tok0 + t;
  }

  const float inv = 1.f / sum;
  const float rsc = 1.f / (esel + EPSV * sum);
  const size_t MN = (size_t)mtok * NG;
  const size_t ob = (size_t)(tok0 + t) * NG + l4 * 16;
#pragma unroll
  for (int jj = 0; jj < 4; ++jj) {
    f32x4 sc, mk, rw;
#pragma unroll
    for (int c = 0; c < 4; ++c) {
      int j = jj * 4 + c;
      float bit = ((taken >> j) & 1u) ? 1.f : 0.f;
      sc[c] = e[j] * inv;
      mk[c] = bit;
      rw[c] = bit * e[j] * rsc;
    }
    *(f32x4*)&out[ob + jj * 4] = rw;
    *(f32x4*)&out[MN + ob + jj * 4] = mk;
    *(f32x4*)&out[2 * MN + ob + jj * 4] = sc;
  }
}

// ---------------- Kernel 2: exact fp32 fixup for near-tie tokens ----------------
__global__ __launch_bounds__(256) void moe_fixup(
    const float* __restrict__ x, const float* __restrict__ W,
    float* __restrict__ out, const int* __restrict__ counter,
    const int* __restrict__ flaglist, int mtok)
{
  const int cnt = counter[0];
  const int wvid = blockIdx.x * 4 + (threadIdx.x >> 6);
  const int lane = threadIdx.x & 63;
  const size_t MN = (size_t)mtok * NG;

  for (int i = wvid; i < cnt; i += 512) {
    const int tok = flaglist[i];
    const float* xr = &x[(size_t)tok * DM];
    const float* wr = &W[(size_t)lane * DM];
    f32x4 a = {0.f, 0.f, 0.f, 0.f};
    for (int k = 0; k < DM; k += 16) {
#pragma unroll
      for (int q = 0; q < 4; ++q)
        a += *(const f32x4*)&xr[k + q * 4] * *(const f32x4*)&wr[k + q * 4];
    }
    float l = a.x + a.y + a.z + a.w;

    float m = l;
#pragma unroll
    for (int msk = 1; msk < 64; msk <<= 1) m = fmaxf(m, __shfl_xor(m, msk));
    float e = __expf(l - m);
    float sum = e;
#pragma unroll
    for (int msk = 1; msk < 64; msk <<= 1) sum += __shfl_xor(sum, msk);

    bool sel = false;
#pragma unroll 1
    for (int p = 0; p < 8; ++p) {
      float bv = sel ? -3.4e38f : l;
      int bi = sel ? 1000 : lane;
#pragma unroll
      for (int msk = 1; msk < 64; msk <<= 1) {
        float ov = __shfl_xor(bv, msk);
        int oi = __shfl_xor(bi, msk);
        bool better = (ov > bv) || (ov == bv && oi < bi);
        bv = better ? ov : bv;
        bi = better ? oi : bi;
      }
      if (bi == lane) sel = true;
    }
    float esel = sel ? e : 0.f;
#pragma unroll
    for (int msk = 1; msk < 64; msk <<= 1) esel += __shfl_xor(esel, msk);

    const float inv = 1.f / sum;
    const float rsc = 1.f / (esel + EPSV * sum);
    const float bit = sel ? 1.f : 0.f;
    const size_t base = (size_t)tok * NG + lane;
    out[base] = bit * e * rsc;
    out[MN + base] = bit;
    out[2 * MN + base] = e * inv;
  }
}

extern "C" void kernel_launch(void* const* d_in, const int* in_sizes, int n_in,
                              void* d_out, int out_size, void* d_ws, size_t ws_size,
                              hipStream_t stream) {
  const float* x = (const float*)d_in[0];
  const float* W = (const float*)d_in[1];
  float* out = (float*)d_out;
  const int mtok = in_sizes[0] / DM;          // 16384

  int* counter = (int*)d_ws;
  int* flaglist = (int*)((char*)d_ws + 64);
  unsigned short* whp = (unsigned short*)((char*)d_ws + 64 + 65536);
  unsigned short* wlp = whp + 131072;         // 256 KB each

  hipLaunchKernelGGL(moe_prep, dim3(64), dim3(256), 0, stream, W, whp, wlp, counter);
  hipLaunchKernelGGL(moe_mfma, dim3(mtok / 64), dim3(256), 0, stream,
                     x, whp, wlp, out, counter, flaglist, mtok);
  hipLaunchKernelGGL(moe_fixup, dim3(128), dim3(256), 0, stream,
                     x, W, out, counter, flaglist, mtok);
}

// Round 5
// 79.174 us; speedup vs baseline: 1.6006x; 1.6006x over previous
//
#include <hip/hip_runtime.h>

#define DM 2048
#define NG 64
#define EPSV 1e-8f
#define TAU 1e-3f

typedef __attribute__((ext_vector_type(4))) float f32x4;
typedef __attribute__((ext_vector_type(16))) float f32x16;
typedef __attribute__((ext_vector_type(4))) int i32x4;
typedef __attribute__((ext_vector_type(4))) unsigned int u32x4;
typedef __attribute__((ext_vector_type(8))) short bf16x8;

__device__ __forceinline__ void stage16(const float* gsrc, float* ldst) {
  __builtin_amdgcn_global_load_lds(
      (const __attribute__((address_space(1))) unsigned int*)gsrc,
      (__attribute__((address_space(3))) unsigned int*)ldst, 16, 0, 0);
}

// split 8 fp32 into hi (truncate) / lo (rne residual) bf16.
__device__ __forceinline__ void split8(f32x4 x0, f32x4 x1, bf16x8& ah, bf16x8& al) {
  u32x4 u0 = __builtin_bit_cast(u32x4, x0);
  u32x4 u1 = __builtin_bit_cast(u32x4, x1);
  i32x4 hi;
  hi.x = (int)((u0.x >> 16) | (u0.y & 0xffff0000u));
  hi.y = (int)((u0.z >> 16) | (u0.w & 0xffff0000u));
  hi.z = (int)((u1.x >> 16) | (u1.y & 0xffff0000u));
  hi.w = (int)((u1.z >> 16) | (u1.w & 0xffff0000u));
  u32x4 m0 = u0 & 0xffff0000u;
  u32x4 m1 = u1 & 0xffff0000u;
  f32x4 r0 = x0 - __builtin_bit_cast(f32x4, m0);
  f32x4 r1 = x1 - __builtin_bit_cast(f32x4, m1);
  int lo0, lo1, lo2, lo3;
  asm("v_cvt_pk_bf16_f32 %0, %1, %2" : "=v"(lo0) : "v"(r0.x), "v"(r0.y));
  asm("v_cvt_pk_bf16_f32 %0, %1, %2" : "=v"(lo1) : "v"(r0.z), "v"(r0.w));
  asm("v_cvt_pk_bf16_f32 %0, %1, %2" : "=v"(lo2) : "v"(r1.x), "v"(r1.y));
  asm("v_cvt_pk_bf16_f32 %0, %1, %2" : "=v"(lo3) : "v"(r1.z), "v"(r1.w));
  i32x4 lo; lo.x = lo0; lo.y = lo1; lo.z = lo2; lo.w = lo3;
  ah = __builtin_bit_cast(bf16x8, hi);
  al = __builtin_bit_cast(bf16x8, lo);
}

// ---------------- Kernel 0: W split + counter reset ----------------
__global__ __launch_bounds__(256) void moe_prep(
    const float* __restrict__ W, unsigned short* __restrict__ whp,
    unsigned short* __restrict__ wlp, int* __restrict__ counter)
{
  int tg = blockIdx.x * 256 + threadIdx.x;   // 128*2*64 fragments
  if (tg == 0) *counter = 0;
  int S = tg >> 7, h = (tg >> 6) & 1, n = tg & 63;
  const float* src = &W[(size_t)n * DM + S * 16 + h * 8];
  f32x4 w0 = *(const f32x4*)&src[0];
  f32x4 w1 = *(const f32x4*)&src[4];
  bf16x8 ah, al;
  split8(w0, w1, ah, al);
  *(bf16x8*)&whp[(size_t)tg * 8] = ah;
  *(bf16x8*)&wlp[(size_t)tg * 8] = al;
}

// ---------------- Kernel 1: split-bf16 MFMA GEMM + epilogue + flag ----------------
// Ring-4 x LDS, FIFO-correct counted vmcnt, stage issued after barrier.
__global__ __launch_bounds__(256, 1) void moe_mfma(
    const float* __restrict__ x, const unsigned short* __restrict__ whp,
    const unsigned short* __restrict__ wlp, float* __restrict__ out,
    int* __restrict__ counter, int* __restrict__ flaglist, int mtok)
{
  __shared__ float xsr[4][64 * 64];   // 64 KB
  __shared__ float lbuf[64][64];      // 16 KB

  const int tid = threadIdx.x;
  const int lane = tid & 63;
  const int wid = tid >> 6;
  const int tm0 = (wid & 1) * 32;
  const int gn0 = (wid >> 1) * 32;
  const int tok0 = blockIdx.x * 64;
  const int h = lane >> 5;
  const int ln = lane & 31;
  const int grp = gn0 + ln;

  auto stage_window = [&](int w, int slot) {
    const float* xb = x + (size_t)tok0 * DM + w * 64;
    float* ld = &xsr[slot][0];
#pragma unroll
    for (int i = 0; i < 4; ++i) {
      int idx = i * 256 + tid;
      int r = idx >> 4, q = idx & 15;
      int sq = q ^ (r & 15);
      stage16(xb + (size_t)r * DM + (sq << 2), ld + (idx << 2));
    }
  };

  bf16x8 Bh[2][4], Bl[2][4];
  f32x16 acc = {0.f,0.f,0.f,0.f,0.f,0.f,0.f,0.f,0.f,0.f,0.f,0.f,0.f,0.f,0.f,0.f};

#define LOADB(WW, SET) do {                                                  \
    int w_ = (WW) < 31 ? (WW) : 31;                                          \
    _Pragma("unroll")                                                        \
    for (int s = 0; s < 4; ++s) {                                            \
      size_t bidx = (((size_t)((w_ * 4 + s) * 2 + h) * 64) + grp) * 8;       \
      Bh[SET][s] = *(const bf16x8*)&whp[bidx];                               \
      Bl[SET][s] = *(const bf16x8*)&wlp[bidx];                               \
    }                                                                        \
  } while (0)

#define COMPUTE(WIN, SET) do {                                               \
    const float* xrow_ = &xsr[(WIN) & 3][(tm0 + ln) * 64];                   \
    const int rsw_ = ((tm0 + ln) & 15);                                      \
    _Pragma("unroll")                                                        \
    for (int s = 0; s < 4; ++s) {                                            \
      int qa = s * 4 + h * 2;                                                \
      f32x4 x0 = *(const f32x4*)&xrow_[((qa ^ rsw_) << 2)];                  \
      f32x4 x1 = *(const f32x4*)&xrow_[(((qa + 1) ^ rsw_) << 2)];            \
      bf16x8 ah, al;                                                         \
      split8(x0, x1, ah, al);                                                \
      acc = __builtin_amdgcn_mfma_f32_32x32x16_bf16(ah, Bh[SET][s], acc, 0, 0, 0); \
      acc = __builtin_amdgcn_mfma_f32_32x32x16_bf16(al, Bh[SET][s], acc, 0, 0, 0); \
      acc = __builtin_amdgcn_mfma_f32_32x32x16_bf16(ah, Bl[SET][s], acc, 0, 0, 0); \
    }                                                                        \
  } while (0)

#define PHASE(WIN, CSET, LSET, VM) do {                                      \
    LOADB((WIN) + 1, LSET);                                                  \
    asm volatile("s_waitcnt vmcnt(" #VM ")" ::: "memory");                   \
    __builtin_amdgcn_s_barrier();                                            \
    __builtin_amdgcn_sched_barrier(0);                                       \
    stage_window(((WIN) + 3) < 31 ? ((WIN) + 3) : 31, ((WIN) + 3) & 3);      \
    COMPUTE(WIN, CSET);                                                      \
  } while (0)

  // prologue: B(0) then 3 windows.  FIFO: LB0(8), st0(4), st1(4), st2(4)
  LOADB(0, 0);
  stage_window(0, 0);
  stage_window(1, 1);
  stage_window(2, 2);

  // peeled first iteration (vmcnt 16 / 24), then steady-state vmcnt 32
  PHASE(0, 0, 1, 16);
  PHASE(1, 1, 0, 24);
#pragma unroll 1
  for (int w2 = 1; w2 < 16; ++w2) {
    const int win = w2 * 2;
    PHASE(win, 0, 1, 32);
    PHASE(win + 1, 1, 0, 32);
  }
#undef PHASE
#undef LOADB
#undef COMPUTE

  // ---- logits -> LDS (quad-rotate swizzled cols) ----
#pragma unroll
  for (int r = 0; r < 16; ++r) {
    int m = tm0 + (r & 3) + 8 * (r >> 2) + 4 * h;
    int colp = ((gn0 + ln) + 4 * (m & 15)) & 63;
    lbuf[m][colp] = acc[r];
  }
  __syncthreads();

  // ---- per-token epilogue: 4 lanes/token ----
  const int t = tid >> 2;
  const int l4 = tid & 3;
  float l[16], e[16];
#pragma unroll
  for (int jj = 0; jj < 4; ++jj) {
    int gb = l4 * 16 + jj * 4;
    int cp = (gb + 4 * (t & 15)) & 63;
    f32x4 v = *(const f32x4*)&lbuf[t][cp];
    l[jj * 4 + 0] = v.x; l[jj * 4 + 1] = v.y;
    l[jj * 4 + 2] = v.z; l[jj * 4 + 3] = v.w;
  }
  float mx = l[0];
#pragma unroll
  for (int j = 1; j < 16; ++j) mx = fmaxf(mx, l[j]);
  mx = fmaxf(mx, __shfl_xor(mx, 1));
  mx = fmaxf(mx, __shfl_xor(mx, 2));
  float sum = 0.f;
#pragma unroll
  for (int j = 0; j < 16; ++j) { e[j] = __expf(l[j] - mx); sum += e[j]; }
  sum += __shfl_xor(sum, 1);
  sum += __shfl_xor(sum, 2);

  unsigned taken = 0;
  float l8 = 0.f, l9 = 0.f;
#pragma unroll 1
  for (int p = 0; p < 9; ++p) {
    float bv = -3.4e38f; int bi = 1000;
#pragma unroll
    for (int j = 0; j < 16; ++j) {
      bool avail = !((taken >> j) & 1u);
      bool better = avail && (l[j] > bv);
      bv = better ? l[j] : bv;
      bi = better ? (l4 * 16 + j) : bi;
    }
#pragma unroll
    for (int msk = 1; msk < 4; msk <<= 1) {
      float ov = __shfl_xor(bv, msk);
      int oi = __shfl_xor(bi, msk);
      bool better = (ov > bv) || (ov == bv && oi < bi);
      bv = better ? ov : bv;
      bi = better ? oi : bi;
    }
    if (p < 8) {
      if ((bi >> 4) == l4) taken |= 1u << (bi & 15);
      if (p == 7) l8 = bv;
    } else {
      l9 = bv;
    }
  }
  float esel = 0.f;
#pragma unroll
  for (int j = 0; j < 16; ++j) esel += ((taken >> j) & 1u) ? e[j] : 0.f;
  esel += __shfl_xor(esel, 1);
  esel += __shfl_xor(esel, 2);

  if ((l8 - l9) < TAU && l4 == 0) {
    int ix = atomicAdd(counter, 1);
    flaglist[ix] = tok0 + t;
  }

  const float inv = 1.f / sum;
  const float rsc = 1.f / (esel + EPSV * sum);
  const size_t MN = (size_t)mtok * NG;
  const size_t ob = (size_t)(tok0 + t) * NG + l4 * 16;
#pragma unroll
  for (int jj = 0; jj < 4; ++jj) {
    f32x4 sc, mk, rw;
#pragma unroll
    for (int c = 0; c < 4; ++c) {
      int j = jj * 4 + c;
      float bit = ((taken >> j) & 1u) ? 1.f : 0.f;
      sc[c] = e[j] * inv;
      mk[c] = bit;
      rw[c] = bit * e[j] * rsc;
    }
    *(f32x4*)&out[ob + jj * 4] = rw;
    *(f32x4*)&out[MN + ob + jj * 4] = mk;
    *(f32x4*)&out[2 * MN + ob + jj * 4] = sc;
  }
}

// ---------------- Kernel 2: exact fp32 fixup, block-per-token ----------------
// 256 threads = 64 groups x 4 K-quarters; LDS reduce; wave-0 epilogue.
__global__ __launch_bounds__(256) void moe_fixup(
    const float* __restrict__ x, const float* __restrict__ W,
    float* __restrict__ out, const int* __restrict__ counter,
    const int* __restrict__ flaglist, int mtok)
{
  const int cnt = counter[0];
  const int g = threadIdx.x & 63;
  const int q = threadIdx.x >> 6;
  const size_t MN = (size_t)mtok * NG;
  __shared__ float part[4][64];

  for (int i = blockIdx.x; i < cnt; i += 256) {
    const int tok = flaglist[i];
    const float* xr = &x[(size_t)tok * DM + q * 512];
    const float* wr = &W[(size_t)g * DM + q * 512];
    f32x4 a = {0.f, 0.f, 0.f, 0.f};
#pragma unroll 8
    for (int k = 0; k < 512; k += 4)
      a += *(const f32x4*)&xr[k] * *(const f32x4*)&wr[k];
    part[q][g] = a.x + a.y + a.z + a.w;
    __syncthreads();

    if (q == 0) {
      float l = part[0][g] + part[1][g] + part[2][g] + part[3][g];

      float m = l;
#pragma unroll
      for (int msk = 1; msk < 64; msk <<= 1) m = fmaxf(m, __shfl_xor(m, msk));
      float e = __expf(l - m);
      float sum = e;
#pragma unroll
      for (int msk = 1; msk < 64; msk <<= 1) sum += __shfl_xor(sum, msk);

      bool sel = false;
#pragma unroll 1
      for (int p = 0; p < 8; ++p) {
        float bv = sel ? -3.4e38f : l;
        int bi = sel ? 1000 : g;
#pragma unroll
        for (int msk = 1; msk < 64; msk <<= 1) {
          float ov = __shfl_xor(bv, msk);
          int oi = __shfl_xor(bi, msk);
          bool better = (ov > bv) || (ov == bv && oi < bi);
          bv = better ? ov : bv;
          bi = better ? oi : bi;
        }
        if (bi == g) sel = true;
      }
      float esel = sel ? e : 0.f;
#pragma unroll
      for (int msk = 1; msk < 64; msk <<= 1) esel += __shfl_xor(esel, msk);

      const float inv = 1.f / sum;
      const float rsc = 1.f / (esel + EPSV * sum);
      const float bit = sel ? 1.f : 0.f;
      const size_t base = (size_t)tok * NG + g;
      out[base] = bit * e * rsc;
      out[MN + base] = bit;
      out[2 * MN + base] = e * inv;
    }
    __syncthreads();
  }
}

extern "C" void kernel_launch(void* const* d_in, const int* in_sizes, int n_in,
                              void* d_out, int out_size, void* d_ws, size_t ws_size,
                              hipStream_t stream) {
  const float* x = (const float*)d_in[0];
  const float* W = (const float*)d_in[1];
  float* out = (float*)d_out;
  const int mtok = in_sizes[0] / DM;          // 16384

  int* counter = (int*)d_ws;
  int* flaglist = (int*)((char*)d_ws + 64);
  unsigned short* whp = (unsigned short*)((char*)d_ws + 64 + 65536);
  unsigned short* wlp = whp + 131072;         // 256 KB each

  hipLaunchKernelGGL(moe_prep, dim3(64), dim3(256), 0, stream, W, whp, wlp, counter);
  hipLaunchKernelGGL(moe_mfma, dim3(mtok / 64), dim3(256), 0, stream,
                     x, whp, wlp, out, counter, flaglist, mtok);
  hipLaunchKernelGGL(moe_fixup, dim3(256), dim3(256), 0, stream,
                     x, W, out, counter, flaglist, mtok);
}